// Round 5
// baseline (131.637 us; speedup 1.0000x reference)
//
#include <hip/hip_runtime.h>
#include <math.h>

// KTVLoss: inputs out_l, out_r, input_i : (8,3,512,512) fp32. Output: 1 fp32 scalar.
//
// Sx = 10x10 box sum of |dI/dh| (502x503), Sy = box sum of |dI/dw| (503x502).
// Reference pairs them by FLAT index: Sx(i,j) with Sy(i,i+j) if i+j<502 else
// Sy(i+1,i+j-502). ratio = (SxL+SyL+SxR+SyR)/(SxI+SyI+1e-4), mean over 24*502*503.
// grad part (fp32): mean|GxL+GxR-GxI| + mean|GyL+GyR-GyI| over 24*511*512 each.
// norm part carries 1e-4 weight -> packed f16 (abs err ~1e-5; validated R4-R9).
//
// R15: R14 refuted the LDS-instr-count theory (halving DS ops = null). The
// remaining all-waves-stalled window is the lgkmcnt(0) WRITE DRAIN before
// each s_barrier: reads are force-retired by compiler consumer waits, so the
// only outstanding ops at the barrier are the ~4 LDS writes (awin+syring);
// lgkmcnt(0) makes all 16 waves drain them through the shared DS pipe's
// backlog in lockstep, every superstep (m97 barrier-drain, lgkm edition).
// Fix = counted lgkm (T4-idiom): barrier waits vmcnt(6) lgkmcnt(4), leaving
// this superstep's <=4 writes in flight. Legal because the pipeline is
// re-lagged so every write has >= 2 supersteps before first read (writes of
// T retire by barrier T+1, since T+1 issues >=10 newer DS ops):
//   SCANROW rows 2T,2T+1 -> awin slot T%3 (depth 3; read at T+2, slot (T+1)%3)
//   PATCHRING rows 2T-4,2T-3 (awin gap 2); syring write rows 2T-13,2T-12
//   RATIO Sx rows 2T-18,2T-17 (syring gap 2; snap = 2-deep shift register)
// Tail supersteps (T>=17: few newer DS ops to age writes out) use lgkm(0).
// 21 supersteps. Structure reverted to R13 (best, 124 VGPR); snap2 adds +2.
// LDS: rows 36,936 + syring 16,064 + awin[3] 25,056 + red 96 = 78,152 B
// => 2 blocks/CU preserved.
//
// VGPR cap law (R4-R7): cap = 256/min_waves; (512,2) -> 128. Watch for spill.

namespace {

constexpr int H = 512, W = 512;
constexpr int CX = W - 10 + 1;   // 503 Sx cols (Sy has 503 rows)
constexpr int CY = W - 10;       // 502 Sy cols
constexpr int RB = 24;           // Sx rows per band
constexpr int NBANDS = (CY + RB - 1) / RB;   // 21
constexpr int NIMG = 24;
constexpr int NBLOCKS = NIMG * NBANDS;       // 504

typedef __fp16 h2 __attribute__((ext_vector_type(2)));

__device__ __forceinline__ int h2i(h2 v) { int r; __builtin_memcpy(&r, &v, 4); return r; }
__device__ __forceinline__ h2 i2h(int v) { h2 r; __builtin_memcpy(&r, &v, 4); return r; }

template <int C, int RM>
__device__ __forceinline__ int dppmov(int v) {
  return __builtin_amdgcn_update_dpp(0, v, C, RM, 0xf, true);
}
// full 64-lane inclusive prefix sum of a f16x2 pack (pure VALU)
__device__ __forceinline__ h2 scan64(h2 v) {
  v += i2h(dppmov<0x111, 0xf>(h2i(v)));  // row_shr:1
  v += i2h(dppmov<0x112, 0xf>(h2i(v)));  // row_shr:2
  v += i2h(dppmov<0x114, 0xf>(h2i(v)));  // row_shr:4
  v += i2h(dppmov<0x118, 0xf>(h2i(v)));  // row_shr:8
  v += i2h(dppmov<0x142, 0xa>(h2i(v)));  // row_bcast15 -> rows 1,3
  v += i2h(dppmov<0x143, 0xc>(h2i(v)));  // row_bcast31 -> rows 2,3
  return v;
}

// async global->LDS, 4 bytes/lane, dest = wave-uniform base + lane*4
__device__ __forceinline__ void gload(const float* g, float* l) {
  __builtin_amdgcn_global_load_lds((const __attribute__((address_space(1))) void*)g,
                                   (__attribute__((address_space(3))) void*)l, 4, 0, 0);
}

// Barrier with counted waits (T4 idiom, vmcnt AND lgkmcnt):
//  vmcnt(6): current superstep's 6 staging loads stay in flight.
//  lgkmcnt(4): current superstep's <=4 LDS writes stay in flight (all reads
//  are already consumer-retired). Writes of T retire by barrier T+1 because
//  T+1 issues >=10 newer DS ops; every written location is first read at T+2.
//  TAIL supersteps issue too few DS ops to age writes out -> full lgkm(0).
// encoding: vmcnt[3:0], expcnt[6:4]=7, lgkmcnt[11:8].
template <bool TAIL>
__device__ __forceinline__ void kbarrier_vm() {
  __builtin_amdgcn_sched_barrier(0);
  __builtin_amdgcn_s_waitcnt(TAIL ? 0x0076 : 0x0476);
  __builtin_amdgcn_s_barrier();
  __builtin_amdgcn_sched_barrier(0);
}

}  // namespace

// ---- stage row Q (clamped) of all 3 images into the depth-6 LDS row ring ----
#define STAGE(Q)                                                                  \
  {                                                                               \
    constexpr int q_ = ((Q) > 33) ? 33 : (Q);                                     \
    int grow = i0 + q_;                                                           \
    if (grow > H - 1) grow = H - 1; /* last band: re-reads row 511, masked */     \
    const int goff = grow * W + j;                                                \
    gload(pL + goff, &rows[q_ % 6][0][wv * 64]);                                  \
    gload(pR + goff, &rows[q_ % 6][1][wv * 64]);                                  \
    gload(pI + goff, &rows[q_ % 6][2][wv * 64]);                                  \
  }

#define ROWRD_DECL(P)                                                             \
  float xV##P##L = 0.f, xV##P##R = 0.f, xV##P##I = 0.f;                           \
  float xN##P##L = 0.f, xN##P##R = 0.f, xN##P##I = 0.f;

// ---- read row S cols j, j+1 from the LDS ring (ds_read2_b32 pairs) ----
#define ROWRD(S, P)                                                               \
  {                                                                               \
    constexpr int sl = (S) % 6;                                                   \
    xV##P##L = rows[sl][0][j]; xN##P##L = rows[sl][0][j + 1];                     \
    xV##P##R = rows[sl][1][j]; xN##P##R = rows[sl][1][j + 1];                     \
    xV##P##I = rows[sl][2][j]; xN##P##I = rows[sl][2][j + 1];                     \
  }

// ---- per-row scan: gradients, pack, DPP scan, prefix -> awin slot WS ----
#define SCANROW(S, P, WS_)                                                        \
  {                                                                               \
    constexpr int s_ = (S);                                                       \
    const int r = i0 + s_;                                                        \
    const float xl = xV##P##L, xr = xV##P##R, xi = xV##P##I;                      \
    const float gyl = xN##P##L - xl, gyr = xN##P##R - xr, gyi = xN##P##I - xi;    \
    const float gxl = xl - prevL, gxr = xr - prevR, gxi = xi - prevI;             \
    prevL = xl; prevR = xr; prevI = xi;                                           \
    if (r < gyEnd && j < W - 1) accGY += fabsf(gyl + gyr - gyi);                  \
    if (s_ > 0 && (r - 1) < gxEnd) accGX += fabsf(gxl + gxr - gxi);               \
    float yn = fabsf(gyl) + fabsf(gyr), yd = fabsf(gyi);                          \
    float xn = fabsf(gxl) + fabsf(gxr), xd = fabsf(gxi);                          \
    if (j == W - 1) { yn = 0.f; yd = 0.f; }                                       \
    if (r >= H) { yn = 0.f; yd = 0.f; xn = 0.f; xd = 0.f; }                       \
    const h2 Y = __builtin_amdgcn_cvt_pkrtz(yn, yd);                              \
    h2 X = (h2)(__fp16)0;                                                         \
    if (s_ != 0) X = __builtin_amdgcn_cvt_pkrtz(xn, xd);                          \
    const h2 AY = scan64(Y), AX = scan64(X);                                      \
    awin[WS_][s_ & 1][j + 1] = make_int2(h2i(AY), h2i(AX));                       \
  }

// ---- window combine + vertical ring for row TT (set P); awin reads were ----
// ---- issued at superstep top, TWO barriers after they were written.     ----
#define PATCHRING(TT, P)                                                          \
  {                                                                               \
    constexpr int t_ = (TT);                                                      \
    constexpr int hs = (t_ + 20) % 10;                                            \
    h2 hh = i2h(w10##P.x), hx = i2h(w10##P.y);                                    \
    if (lane != 0) { hh -= i2h(w0##P.x); hx -= i2h(w0##P.y); }                    \
    if (patch) { hh += i2h(wT##P.x); hx += i2h(wT##P.y); }                        \
    runY += hh - histY[hs]; histY[hs] = hh;                                       \
    runX += hx - histX[hs]; histX[hs] = hx;                                       \
    snap1##P = runX; /* Sx row t_-10; consumed 2 supersteps later via snap2 */    \
    if (t_ >= 9) {                                                                \
      const int iY = (i0 + t_) - 9;                                               \
      if (iY <= sxEnd && j < CY) syring[iY & 7][j] = h2i(runY);                   \
    }                                                                             \
  }

// ---- ratio for Sx row U: issue syring read at superstep top ... ----
#define RATIO_RD(U, P)                                                            \
  int syrd##P = 0, uok##P = 0;                                                    \
  {                                                                               \
    constexpr int u_ = (U);                                                       \
    if (u_ >= 0) {                                                                \
      const int iX = i0 + u_;                                                     \
      if (iX < sxEnd && j < CX) {                                                 \
        int jy = iX + j, rw = iX;                                                 \
        if (jy >= CY) { jy -= CY; ++rw; }                                         \
        syrd##P = syring[rw & 7][jy];                                             \
        uok##P = 1;                                                               \
      }                                                                           \
    }                                                                             \
  }

// ---- ... consume it with the 2-superstep-old snap (snap2) ----
#define RATIO_FIN(P)                                                              \
  if (uok##P) {                                                                   \
    const h2 sy = i2h(syrd##P);                                                   \
    const float num = (float)snap2##P.x + (float)sy.x;                            \
    const float den = (float)snap2##P.y + (float)sy.y + 1e-4f;                    \
    accN += num * __builtin_amdgcn_rcpf(den);                                     \
  }

// ---- 2-row superstep: reads at top, stage, ratio, snap-shift, patch/ring, ----
// ---- scans, counted-vmcnt + counted-lgkm barrier.                          ----
#define SUPER(T_)                                                                 \
  {                                                                               \
    constexpr int tT = (T_);                                                      \
    constexpr int WS = tT % 3;        /* awin write slot */                       \
    constexpr int RS = (tT + 1) % 3;  /* awin read slot (= (tT-2)%3) */           \
    constexpr int a0 = 2 * tT, a1 = a0 + 1;                                       \
    RATIO_RD(a0 - 18, A)                                                          \
    RATIO_RD(a0 - 17, B)                                                          \
    int2 w0A = make_int2(0, 0), w10A = w0A, wTA = w0A;                            \
    int2 w0B = w0A, w10B = w0A, wTB = w0A;                                        \
    if (tT >= 2) { /* prefix packs of rows a0-4 (A), a0-3 (B), written T-2 */     \
      w0A  = awin[RS][0][j];       w10A = awin[RS][0][j + 10];                    \
      wTA  = awin[RS][0][wtop];                                                   \
      w0B  = awin[RS][1][j];       w10B = awin[RS][1][j + 10];                    \
      wTB  = awin[RS][1][wtop];                                                   \
    }                                                                             \
    ROWRD_DECL(A) ROWRD_DECL(B)                                                   \
    if (a0 <= 33) { ROWRD(a0, A) ROWRD(a1, B) }                                   \
    STAGE(a0 + 4) STAGE(a0 + 5)                                                   \
    RATIO_FIN(A) RATIO_FIN(B)                                                     \
    snap2A = snap1A; snap2B = snap1B;  /* 2-deep delay line */                    \
    if (tT >= 2 && (a0 - 4) <= 33) {                                              \
      PATCHRING(a0 - 4, A)                                                        \
      PATCHRING(a0 - 3, B)                                                        \
    }                                                                             \
    if (a0 <= 33) {                                                               \
      SCANROW(a0, A, WS)                                                          \
      SCANROW(a1, B, WS)                                                          \
    }                                                                             \
    kbarrier_vm<(tT >= 17)>();                                                    \
  }

__global__ __launch_bounds__(512, 2) void ktv_main(const float* __restrict__ L,
                                                   const float* __restrict__ R,
                                                   const float* __restrict__ I,
                                                   double* __restrict__ partial) {
  const int blk = blockIdx.x;
  const int img = blk / NBANDS;
  const int band = blk % NBANDS;
  const int i0 = band * RB;
  const int j = threadIdx.x;  // column
  const int lane = j & 63;
  const int wv = j >> 6;
  const int wtop = (wv + 1) << 6;            // awin slot holding own wave's total
  const bool patch = (lane >= 55) && (wv < 7);  // window crosses into next wave

  const bool lastb = (band == NBANDS - 1);
  const int gyEnd = lastb ? H : (i0 + RB);        // Gy rows owned: [i0, gyEnd)
  const int gxEnd = lastb ? (H - 1) : (i0 + RB);  // Gx rows owned: [i0, gxEnd)
  const int sxEnd = lastb ? CY : (i0 + RB);       // Sx rows owned: [i0, sxEnd)

  const size_t base = (size_t)img * (H * W);
  const float* pL = L + base;
  const float* pR = R + base;
  const float* pI = I + base;

  __shared__ float rows[6][3][513];    // staged input rows, depth-6 ring (+pad col)
  __shared__ int syring[8][CY];        // completed Sy rows (f16x2 n,d), depth-8 ring
  __shared__ int2 awin[3][2][522];     // prefix packs, depth-3 (write T, read T+2)
                                       // slot k = prefix through col k-1; [64w] = T_{w-1}
  __shared__ float redN[8], redGX[8], redGY[8];

  h2 histY[10], histX[10];
#pragma unroll
  for (int t = 0; t < 10; ++t) { histY[t] = (h2)(__fp16)0; histX[t] = (h2)(__fp16)0; }
  h2 runY = (h2)(__fp16)0, runX = (h2)(__fp16)0;
  h2 snap1A = (h2)(__fp16)0, snap1B = snap1A, snap2A = snap1A, snap2B = snap1A;
  float accN = 0.f, accGX = 0.f, accGY = 0.f;
  float prevL = 0.f, prevR = 0.f, prevI = 0.f;

  // prologue: stage rows 0..3 (12 loads); zero the j=512 pad entries
  STAGE(0) STAGE(1) STAGE(2) STAGE(3)
  if (j < 18) rows[j / 3][j % 3][512] = 0.f;
  __builtin_amdgcn_sched_barrier(0);
  __builtin_amdgcn_s_waitcnt(0x0076);  // vmcnt(6): rows 0,1 landed; lgkm(0)
  __builtin_amdgcn_s_barrier();
  __builtin_amdgcn_sched_barrier(0);

  // 21 supersteps: scans T=0..16 (rows 0..33), PATCH T=2..18, RATIO T=9..20
  SUPER(0)  SUPER(1)  SUPER(2)  SUPER(3)  SUPER(4)  SUPER(5)
  SUPER(6)  SUPER(7)  SUPER(8)  SUPER(9)  SUPER(10) SUPER(11)
  SUPER(12) SUPER(13) SUPER(14) SUPER(15) SUPER(16) SUPER(17)
  SUPER(18) SUPER(19) SUPER(20)

  // block reduction
#pragma unroll
  for (int o2 = 32; o2 > 0; o2 >>= 1) {
    accN  += __shfl_down(accN, o2);
    accGX += __shfl_down(accGX, o2);
    accGY += __shfl_down(accGY, o2);
  }
  if (lane == 0) { redN[wv] = accN; redGX[wv] = accGX; redGY[wv] = accGY; }
  __syncthreads();
  if (j == 0) {
    float n = 0.f, gx = 0.f, gy = 0.f;
#pragma unroll
    for (int w2 = 0; w2 < 8; ++w2) { n += redN[w2]; gx += redGX[w2]; gy += redGY[w2]; }
    double* p = partial + (size_t)blk * 3;
    p[0] = (double)n; p[1] = (double)gx; p[2] = (double)gy;
  }
}

__global__ __launch_bounds__(64) void ktv_reduce(const double* __restrict__ partial,
                                                 float* __restrict__ out) {
  double n = 0.0, gx = 0.0, gy = 0.0;
  for (int i = threadIdx.x; i < NBLOCKS; i += 64) {
    const double* p = partial + (size_t)i * 3;
    n += p[0]; gx += p[1]; gy += p[2];
  }
#pragma unroll
  for (int o2 = 32; o2 > 0; o2 >>= 1) {
    n  += __shfl_down(n, o2);
    gx += __shfl_down(gx, o2);
    gy += __shfl_down(gy, o2);
  }
  if (threadIdx.x == 0) {
    const double norm_loss = n / 6060144.0;          // 24*502*503
    const double grad_loss = (gx + gy) / 6279168.0;  // 24*511*512
    out[0] = (float)(1e-4 * norm_loss + grad_loss);
  }
}

extern "C" void kernel_launch(void* const* d_in, const int* in_sizes, int n_in,
                              void* d_out, int out_size, void* d_ws, size_t ws_size,
                              hipStream_t stream) {
  (void)in_sizes; (void)n_in; (void)out_size; (void)ws_size;
  const float* L = (const float*)d_in[0];
  const float* R = (const float*)d_in[1];
  const float* I = (const float*)d_in[2];
  double* partial = (double*)d_ws;   // NBLOCKS*3 doubles = 12096 B
  float* out = (float*)d_out;

  hipLaunchKernelGGL(ktv_main, dim3(NBLOCKS), dim3(512), 0, stream, L, R, I, partial);
  hipLaunchKernelGGL(ktv_reduce, dim3(1), dim3(64), 0, stream, partial, out);
}

// Round 6
// 123.415 us; speedup vs baseline: 1.0666x; 1.0666x over previous
//
#include <hip/hip_runtime.h>
#include <math.h>

// KTVLoss: inputs out_l, out_r, input_i : (8,3,512,512) fp32. Output: 1 fp32 scalar.
//
// Sx = 10x10 box sum of |dI/dh| (502x503), Sy = box sum of |dI/dw| (503x502).
// Reference pairs them by FLAT index: Sx(i,j) with Sy(i,i+j) if i+j<502 else
// Sy(i+1,i+j-502). ratio = (SxL+SyL+SxR+SyR)/(SxI+SyI+1e-4), mean over 24*502*503.
// grad part (fp32): mean|GxL+GxR-GxI| + mean|GyL+GyR-GyI| over 24*511*512 each.
// norm part carries 1e-4 weight -> packed f16 (abs err ~1e-5; validated R4-R9).
//
// R16: the cost invariant under R11-R15's restructures is the ~32 KB of
// FULLY-UNROLLED straight-line text: zero I-cache reuse, 16 lockstep waves
// streaming ~500 cold lines per block (~1-3k cyc/superstep) - matches the
// unexplained ~3400 cyc/superstep stall and explains why deleting VALU work
// (R14) lowered VALUBusy but not time. The unroll existed only because the
// VGPR hist ring needs static indices. This round RE-ROLLS the loop:
//  - hist ring -> 10-deep shift-register queue (constant-index shift by 2,
//    stays in registers; retire hq[0],hq[1], insert at [8],[9]).
//  - all LDS ring offsets computed from T in SALU (runtime LDS offsets are
//    fine; only VGPR-array dynamic indexing goes to scratch).
//  - constexpr guards -> block-uniform runtime branches.
//  - staging keeps clamp-duplicate semantics => uniform vmcnt(6) cadence.
//  - schedule identical to R13 (validated): ROWRD/awin-read/syring-read at
//    top, stage, scans(+awin writes, now aged before the drain), ratio-fin
//    (snap from T-1), patch(+syring writes), barrier vmcnt(6)+lgkm(0).
//  - accGX+accGY merged (same denominator) -> one accumulator.
// Body ~230 instr ~1.8 KB, hot from iteration 2. Text ~32 KB -> ~4 KB.
//
// VGPR cap law (R4-R7): cap = 256/min_waves; (512,2) -> 128. Watch for spill
// (symptom: WRITE_SIZE >> 20 KB).

namespace {

constexpr int H = 512, W = 512;
constexpr int CX = W - 10 + 1;   // 503 Sx cols (Sy has 503 rows)
constexpr int CY = W - 10;       // 502 Sy cols
constexpr int RB = 24;           // Sx rows per band
constexpr int NBANDS = (CY + RB - 1) / RB;   // 21
constexpr int NIMG = 24;
constexpr int NBLOCKS = NIMG * NBANDS;       // 504

constexpr int ROWSZ = 3 * 513;   // floats per row-slot (L,R,I channels + pad col)

typedef __fp16 h2 __attribute__((ext_vector_type(2)));

__device__ __forceinline__ int h2i(h2 v) { int r; __builtin_memcpy(&r, &v, 4); return r; }
__device__ __forceinline__ h2 i2h(int v) { h2 r; __builtin_memcpy(&r, &v, 4); return r; }

template <int C, int RM>
__device__ __forceinline__ int dppmov(int v) {
  return __builtin_amdgcn_update_dpp(0, v, C, RM, 0xf, true);
}
// full 64-lane inclusive prefix sum of a f16x2 pack (pure VALU)
__device__ __forceinline__ h2 scan64(h2 v) {
  v += i2h(dppmov<0x111, 0xf>(h2i(v)));  // row_shr:1
  v += i2h(dppmov<0x112, 0xf>(h2i(v)));  // row_shr:2
  v += i2h(dppmov<0x114, 0xf>(h2i(v)));  // row_shr:4
  v += i2h(dppmov<0x118, 0xf>(h2i(v)));  // row_shr:8
  v += i2h(dppmov<0x142, 0xa>(h2i(v)));  // row_bcast15 -> rows 1,3
  v += i2h(dppmov<0x143, 0xc>(h2i(v)));  // row_bcast31 -> rows 2,3
  return v;
}

// async global->LDS, 4 bytes/lane, dest = wave-uniform base + lane*4
__device__ __forceinline__ void gload(const float* g, float* l) {
  __builtin_amdgcn_global_load_lds((const __attribute__((address_space(1))) void*)g,
                                   (__attribute__((address_space(3))) void*)l, 4, 0, 0);
}

// barrier with COUNTED vmcnt(6): lgkmcnt(0) for LDS visibility; the current
// superstep's 6 staging loads stay in flight across the barrier (never 0).
// encoding: vmcnt[3:0]=6, exp[6:4]=7(max), lgkm[11:8]=0.
__device__ __forceinline__ void kbarrier_vm() {
  __builtin_amdgcn_sched_barrier(0);
  __builtin_amdgcn_s_waitcnt(0x0076);
  __builtin_amdgcn_s_barrier();
  __builtin_amdgcn_sched_barrier(0);
}

}  // namespace

__global__ __launch_bounds__(512, 2) void ktv_main(const float* __restrict__ L,
                                                   const float* __restrict__ R,
                                                   const float* __restrict__ I,
                                                   double* __restrict__ partial) {
  const int blk = blockIdx.x;
  const int img = blk / NBANDS;
  const int band = blk % NBANDS;
  const int i0 = band * RB;
  const int j = threadIdx.x;  // column
  const int lane = j & 63;
  const int wv = j >> 6;
  const int wtop = (wv + 1) << 6;               // awin slot holding own wave's total
  const bool patch = (lane >= 55) && (wv < 7);  // window crosses into next wave

  const bool lastb = (band == NBANDS - 1);
  const int gyEnd = lastb ? H : (i0 + RB);        // Gy rows owned: [i0, gyEnd)
  const int gxEnd = lastb ? (H - 1) : (i0 + RB);  // Gx rows owned: [i0, gxEnd)
  const int sxEnd = lastb ? CY : (i0 + RB);       // Sx rows owned: [i0, sxEnd)

  const size_t base = (size_t)img * (H * W);
  const float* pL = L + base;
  const float* pR = R + base;
  const float* pI = I + base;

  __shared__ float rows[6 * ROWSZ];   // staged input rows, depth-6 ring (+pad col)
  __shared__ int syring[8 * CY];      // completed Sy rows (f16x2 n,d), depth-8 ring
  __shared__ int2 awin[2 * 2 * 522];  // prefix packs [parity][rowpar][col]
                                      // col k = prefix through col k-1; [64w]=T_{w-1}
  __shared__ float redN[8], redG[8];

  // hist as a 10-deep shift-register queue (registers; constant-index shift)
  h2 hqY[10], hqX[10];
#pragma unroll
  for (int t = 0; t < 10; ++t) { hqY[t] = (h2)(__fp16)0; hqX[t] = (h2)(__fp16)0; }
  h2 runY = (h2)(__fp16)0, runX = (h2)(__fp16)0;
  h2 snapA = (h2)(__fp16)0, snapB = snapA;
  float accN = 0.f, accG = 0.f;
  float prevL = 0.f, prevR = 0.f, prevI = 0.f;

  // prologue: stage rows 0..3 (12 loads; i0+3 <= 483, no clamp needed)
#pragma unroll
  for (int q = 0; q < 4; ++q) {
    const int g = (i0 + q) * W + j;
    gload(pL + g, &rows[q * ROWSZ + wv * 64]);
    gload(pR + g, &rows[q * ROWSZ + 513 + wv * 64]);
    gload(pI + g, &rows[q * ROWSZ + 1026 + wv * 64]);
  }
  if (j < 18) rows[(j / 3) * ROWSZ + (j % 3) * 513 + 512] = 0.f;  // zero pad col
  __builtin_amdgcn_sched_barrier(0);
  __builtin_amdgcn_s_waitcnt(0x0076);  // vmcnt(6): rows 0,1 landed; lgkm(0)
  __builtin_amdgcn_s_barrier();
  __builtin_amdgcn_sched_barrier(0);

  // 19 supersteps, ROLLED: scans T=0..16 (rows 0..33), patch T=1..17, ratio T=7..18
#pragma clang loop unroll(disable)
  for (int T = 0; T < 19; ++T) {
    const bool doScan = (T <= 16);
    const bool doPatch = (T >= 1) && (T <= 17);
    const bool doRatio = (T >= 7);
    const int aWr = (T & 1) * 1044;   // awin write parity base (int2 elems)
    const int aRd = aWr ^ 1044;       // awin read parity base (written at T-1)

    // ---- top: syring reads for ratio rows 2T-14 / 2T-13 ----
    int syrdA = 0, syrdB = 0;
    bool uokA = false, uokB = false;
    if (doRatio) {
      const int iXA = i0 + 2 * T - 14;
      if (iXA < sxEnd && j < CX) {
        int jy = iXA + j, rw = iXA;
        if (jy >= CY) { jy -= CY; ++rw; }
        syrdA = syring[(rw & 7) * CY + jy];
        uokA = true;
      }
      const int iXB = iXA + 1;
      if (iXB < sxEnd && j < CX) {
        int jy = iXB + j, rw = iXB;
        if (jy >= CY) { jy -= CY; ++rw; }
        syrdB = syring[(rw & 7) * CY + jy];
        uokB = true;
      }
    }

    // ---- top: awin prefix reads for patch rows 2T-2 / 2T-1 (written T-1) ----
    int2 w0A = make_int2(0, 0), w10A = w0A, wTA = w0A;
    int2 w0B = w0A, w10B = w0A, wTB = w0A;
    if (doPatch) {
      w0A = awin[aRd + j];        w10A = awin[aRd + j + 10];
      wTA = awin[aRd + wtop];
      w0B = awin[aRd + 522 + j];  w10B = awin[aRd + 522 + j + 10];
      wTB = awin[aRd + 522 + wtop];
    }

    // ---- top: row reads (rows 2T, 2T+1), cols j and j+1 ----
    float xVAL = 0.f, xVAR = 0.f, xVAI = 0.f, xNAL = 0.f, xNAR = 0.f, xNAI = 0.f;
    float xVBL = 0.f, xVBR = 0.f, xVBI = 0.f, xNBL = 0.f, xNBR = 0.f, xNBI = 0.f;
    if (doScan) {
      const int ro = ((2 * T) % 6) * ROWSZ;
      xVAL = rows[ro + j];        xNAL = rows[ro + j + 1];
      xVAR = rows[ro + 513 + j];  xNAR = rows[ro + 513 + j + 1];
      xVAI = rows[ro + 1026 + j]; xNAI = rows[ro + 1026 + j + 1];
      const int rb = ro + ROWSZ;  // slot (2T+1)%6 = (2T)%6+1, never wraps
      xVBL = rows[rb + j];        xNBL = rows[rb + j + 1];
      xVBR = rows[rb + 513 + j];  xNBR = rows[rb + 513 + j + 1];
      xVBI = rows[rb + 1026 + j]; xNBI = rows[rb + 1026 + j + 1];
    }

    // ---- stage rows 2T+4 / 2T+5 (clamp-dup at tail keeps vmcnt cadence) ----
    {
      int s0 = 2 * T + 4; if (s0 > 33) s0 = 33;
      int s1 = 2 * T + 5; if (s1 > 33) s1 = 33;
      const int d0 = (s0 % 6) * ROWSZ, d1 = (s1 % 6) * ROWSZ;
      int g0 = i0 + s0; if (g0 > H - 1) g0 = H - 1; g0 = g0 * W + j;
      int g1 = i0 + s1; if (g1 > H - 1) g1 = H - 1; g1 = g1 * W + j;
      gload(pL + g0, &rows[d0 + wv * 64]);
      gload(pR + g0, &rows[d0 + 513 + wv * 64]);
      gload(pI + g0, &rows[d0 + 1026 + wv * 64]);
      gload(pL + g1, &rows[d1 + wv * 64]);
      gload(pR + g1, &rows[d1 + 513 + wv * 64]);
      gload(pI + g1, &rows[d1 + 1026 + wv * 64]);
    }

    // ---- scans rows 2T, 2T+1: gradients, pack, DPP scan -> awin writes ----
    // (writes issued here, ~100 instrs before the barrier drain)
    if (doScan) {
      const int rA = i0 + 2 * T;
      {  // row A
        const float xl = xVAL, xr = xVAR, xi = xVAI;
        const float gyl = xNAL - xl, gyr = xNAR - xr, gyi = xNAI - xi;
        const float gxl = xl - prevL, gxr = xr - prevR, gxi = xi - prevI;
        prevL = xl; prevR = xr; prevI = xi;
        if (rA < gyEnd && j < W - 1) accG += fabsf(gyl + gyr - gyi);
        if (rA > i0 && (rA - 1) < gxEnd) accG += fabsf(gxl + gxr - gxi);
        float yn = fabsf(gyl) + fabsf(gyr), yd = fabsf(gyi);
        float xn = fabsf(gxl) + fabsf(gxr), xd = fabsf(gxi);
        if (j == W - 1) { yn = 0.f; yd = 0.f; }
        if (rA >= H) { yn = 0.f; yd = 0.f; xn = 0.f; xd = 0.f; }
        const h2 Y = __builtin_amdgcn_cvt_pkrtz(yn, yd);
        h2 X = (h2)(__fp16)0;
        if (rA != i0) X = __builtin_amdgcn_cvt_pkrtz(xn, xd);
        const h2 AY = scan64(Y), AX = scan64(X);
        awin[aWr + (j + 1)] = make_int2(h2i(AY), h2i(AX));
      }
      {  // row B
        const int rB = rA + 1;
        const float xl = xVBL, xr = xVBR, xi = xVBI;
        const float gyl = xNBL - xl, gyr = xNBR - xr, gyi = xNBI - xi;
        const float gxl = xl - prevL, gxr = xr - prevR, gxi = xi - prevI;
        prevL = xl; prevR = xr; prevI = xi;
        if (rB < gyEnd && j < W - 1) accG += fabsf(gyl + gyr - gyi);
        if ((rB - 1) < gxEnd) accG += fabsf(gxl + gxr - gxi);
        float yn = fabsf(gyl) + fabsf(gyr), yd = fabsf(gyi);
        float xn = fabsf(gxl) + fabsf(gxr), xd = fabsf(gxi);
        if (j == W - 1) { yn = 0.f; yd = 0.f; }
        if (rB >= H) { yn = 0.f; yd = 0.f; xn = 0.f; xd = 0.f; }
        const h2 Y = __builtin_amdgcn_cvt_pkrtz(yn, yd);
        const h2 X = __builtin_amdgcn_cvt_pkrtz(xn, xd);  // rB != i0 always
        const h2 AY = scan64(Y), AX = scan64(X);
        awin[aWr + 522 + (j + 1)] = make_int2(h2i(AY), h2i(AX));
      }
    }

    // ---- ratio finish: snaps from T-1 (Sx rows 2T-14 / 2T-13) ----
    if (uokA) {
      const h2 sy = i2h(syrdA);
      const float num = (float)snapA.x + (float)sy.x;
      const float den = (float)snapA.y + (float)sy.y + 1e-4f;
      accN += num * __builtin_amdgcn_rcpf(den);
    }
    if (uokB) {
      const h2 sy = i2h(syrdB);
      const float num = (float)snapB.x + (float)sy.x;
      const float den = (float)snapB.y + (float)sy.y + 1e-4f;
      accN += num * __builtin_amdgcn_rcpf(den);
    }

    // ---- patch rows 2T-2 / 2T-1: window combine, vertical ring, syring ----
    if (doPatch) {
      // row A (t_ = 2T-2)
      h2 hhA = i2h(w10A.x), hxA = i2h(w10A.y);
      if (lane != 0) { hhA -= i2h(w0A.x); hxA -= i2h(w0A.y); }
      if (patch) { hhA += i2h(wTA.x); hxA += i2h(wTA.y); }
      runY += hhA - hqY[0]; runX += hxA - hqX[0];
      snapA = runX;
      {
        const int iY = i0 + 2 * T - 11;
        if (T >= 6 && iY <= sxEnd && j < CY) syring[(iY & 7) * CY + j] = h2i(runY);
      }
      // row B (t_ = 2T-1)
      h2 hhB = i2h(w10B.x), hxB = i2h(w10B.y);
      if (lane != 0) { hhB -= i2h(w0B.x); hxB -= i2h(w0B.y); }
      if (patch) { hhB += i2h(wTB.x); hxB += i2h(wTB.y); }
      runY += hhB - hqY[1]; runX += hxB - hqX[1];
      snapB = runX;
      {
        const int iY = i0 + 2 * T - 10;
        if (T >= 5 && iY <= sxEnd && j < CY) syring[(iY & 7) * CY + j] = h2i(runY);
      }
      // queue: shift by 2, insert the two new window values
#pragma unroll
      for (int k = 0; k < 8; ++k) { hqY[k] = hqY[k + 2]; hqX[k] = hqX[k + 2]; }
      hqY[8] = hhA; hqX[8] = hxA;
      hqY[9] = hhB; hqX[9] = hxB;
    }

    kbarrier_vm();
  }

  // block reduction (2 channels)
#pragma unroll
  for (int o2 = 32; o2 > 0; o2 >>= 1) {
    accN += __shfl_down(accN, o2);
    accG += __shfl_down(accG, o2);
  }
  if (lane == 0) { redN[wv] = accN; redG[wv] = accG; }
  __syncthreads();
  if (j == 0) {
    float n = 0.f, g = 0.f;
#pragma unroll
    for (int w2 = 0; w2 < 8; ++w2) { n += redN[w2]; g += redG[w2]; }
    double* p = partial + (size_t)blk * 2;
    p[0] = (double)n; p[1] = (double)g;
  }
}

__global__ __launch_bounds__(64) void ktv_reduce(const double* __restrict__ partial,
                                                 float* __restrict__ out) {
  double n = 0.0, g = 0.0;
  for (int i = threadIdx.x; i < NBLOCKS; i += 64) {
    const double* p = partial + (size_t)i * 2;
    n += p[0]; g += p[1];
  }
#pragma unroll
  for (int o2 = 32; o2 > 0; o2 >>= 1) {
    n += __shfl_down(n, o2);
    g += __shfl_down(g, o2);
  }
  if (threadIdx.x == 0) {
    const double norm_loss = n / 6060144.0;  // 24*502*503
    const double grad_loss = g / 6279168.0;  // 24*511*512 (gx and gy share denom)
    out[0] = (float)(1e-4 * norm_loss + grad_loss);
  }
}

extern "C" void kernel_launch(void* const* d_in, const int* in_sizes, int n_in,
                              void* d_out, int out_size, void* d_ws, size_t ws_size,
                              hipStream_t stream) {
  (void)in_sizes; (void)n_in; (void)out_size; (void)ws_size;
  const float* L = (const float*)d_in[0];
  const float* R = (const float*)d_in[1];
  const float* I = (const float*)d_in[2];
  double* partial = (double*)d_ws;  // NBLOCKS*2 doubles = 8064 B
  float* out = (float*)d_out;

  hipLaunchKernelGGL(ktv_main, dim3(NBLOCKS), dim3(512), 0, stream, L, R, I, partial);
  hipLaunchKernelGGL(ktv_reduce, dim3(1), dim3(64), 0, stream, partial, out);
}